// Round 16
// baseline (86.362 us; speedup 1.0000x reference)
//
#include <hip/hip_runtime.h>
#include <hip/hip_bf16.h>

#define NSP 2304   // 48*48 spatial
#define NB  4      // batch

typedef unsigned short u16;
typedef __attribute__((ext_vector_type(8))) short short8;
typedef __attribute__((ext_vector_type(4))) float f32x4;
typedef __attribute__((ext_vector_type(4))) unsigned short u16x4;

// scale * log2(e), folded into Q at QKV-GEMM epilogue: softmax p = exp2(S)
#define K1S 0.25508040852656425f

static __device__ inline u16 f2bf(float f) {
  return __builtin_bit_cast(unsigned short, __float2bfloat16(f));
}
// packed f32x2 -> bf16x2 (RNE), single VALU inst; lo16 = cvt(a), hi16 = cvt(b)
static __device__ inline unsigned cvtpk(float a, float b) {
  unsigned r;
  asm("v_cvt_pk_bf16_f32 %0, %1, %2" : "=v"(r) : "v"(a), "v"(b));
  return r;
}

// ---------------------------------------------------------------------------
// prep: x fp32 [b][256][2304] -> xT bf16 [b][2304][256] (single pass).
// ---------------------------------------------------------------------------
__global__ __launch_bounds__(256) void transpose_x(
    const float* __restrict__ x, u16* __restrict__ xT) {
  __shared__ float tile[32][33];
  const int t = threadIdx.x;
  const int n0 = blockIdx.x * 32, c0 = blockIdx.y * 32, b = blockIdx.z;
  const float* xb = x + ((size_t)b * 256 + c0) * NSP + n0;
#pragma unroll
  for (int e = t; e < 1024; e += 256) {
    int cc = e >> 5, nn = e & 31;
    tile[cc][nn] = xb[(size_t)cc * NSP + nn];
  }
  __syncthreads();
  u16* xTb = xT + ((size_t)b * NSP + n0) * 256 + c0;
#pragma unroll
  for (int e = t; e < 1024; e += 256) {
    int nn = e >> 5, cc = e & 31;
    xTb[(size_t)nn * 256 + cc] = f2bf(tile[cc][nn]);
  }
}

// ---------------------------------------------------------------------------
// bf16 MFMA GEMM, A fused-converted from fp32 weights (cvtpk staging),
// B staged from a bf16 [N][256] matrix (xT for EPI0, attnoT for EPI1).
// D = W (Mx256) * B[b] (Nx256)^T, 64x64 tile, 4 waves (2x2 of 32x32).
// EPI 0: rows <256 q (pre-scaled K1S), 256..511 k -> qkT[b][n][512] bf16;
//        rows >=512 v -> vbuf[b][256][2304] bf16.
// EPI 1: fp32 out + bias.
// ---------------------------------------------------------------------------
template <int EPI>
__global__ __launch_bounds__(256) void gemm_mfma(
    const float* __restrict__ W, const u16* __restrict__ Bbf,
    u16* __restrict__ qkT, u16* __restrict__ vbuf,
    float* __restrict__ outf, const float* __restrict__ bias, int N) {
  __shared__ u16 As[64][264];
  __shared__ u16 Bs[64][264];
  const int t = threadIdx.x, lane = t & 63, wid = t >> 6;
  const int lo = lane & 15, g = lane >> 4;
  const int wr = wid >> 1, wc = wid & 1;
  const int row0 = blockIdx.y * 64, col0 = blockIdx.x * 64, b = blockIdx.z;

  // ---- A: fp32 weights -> bf16 LDS (cvtpk pairs) ----
  {
    const int sr = t >> 2, c4 = (t & 3) * 64;
    const float* Arow = W + (size_t)(row0 + sr) * 256 + c4;
#pragma unroll
    for (int i = 0; i < 8; ++i) {
      float4 va = *(const float4*)(Arow + i * 8);
      float4 vb = *(const float4*)(Arow + i * 8 + 4);
      uint4 p = {cvtpk(va.x, va.y), cvtpk(va.z, va.w),
                 cvtpk(vb.x, vb.y), cvtpk(vb.z, vb.w)};
      *(uint4*)&As[sr][c4 + i * 8] = p;
    }
  }
  // ---- B: bf16 rows, coalesced b128 ----
  {
    const int sr = t >> 2, c4 = (t & 3) * 64;
    const u16* Brow = Bbf + ((size_t)b * N + col0 + sr) * 256 + c4;
#pragma unroll
    for (int i = 0; i < 8; ++i)
      *(uint4*)&Bs[sr][c4 + i * 8] = *(const uint4*)(Brow + i * 8);
  }
  __syncthreads();

  f32x4 acc[2][2];
#pragma unroll
  for (int i = 0; i < 2; ++i)
#pragma unroll
    for (int j = 0; j < 2; ++j) acc[i][j] = (f32x4){0, 0, 0, 0};

  const int ar0 = wr * 32 + lo, br0 = wc * 32 + lo;
#pragma unroll
  for (int kk = 0; kk < 8; ++kk) {
    int kc = kk * 32 + g * 8;
    short8 a0 = *(const short8*)&As[ar0][kc];
    short8 a1 = *(const short8*)&As[ar0 + 16][kc];
    short8 b0 = *(const short8*)&Bs[br0][kc];
    short8 b1 = *(const short8*)&Bs[br0 + 16][kc];
    acc[0][0] = __builtin_amdgcn_mfma_f32_16x16x32_bf16(a0, b0, acc[0][0], 0, 0, 0);
    acc[0][1] = __builtin_amdgcn_mfma_f32_16x16x32_bf16(a0, b1, acc[0][1], 0, 0, 0);
    acc[1][0] = __builtin_amdgcn_mfma_f32_16x16x32_bf16(a1, b0, acc[1][0], 0, 0, 0);
    acc[1][1] = __builtin_amdgcn_mfma_f32_16x16x32_bf16(a1, b1, acc[1][1], 0, 0, 0);
  }

  const float qs = (EPI == 0 && row0 < 256) ? K1S : 1.0f;
#pragma unroll
  for (int m2 = 0; m2 < 2; ++m2)
#pragma unroll
    for (int n2 = 0; n2 < 2; ++n2) {
      int m = row0 + wr * 32 + m2 * 16 + g * 4;
      int n = col0 + wc * 32 + n2 * 16 + lo;
      if constexpr (EPI == 0) {
        if (row0 < 512) {  // q,k -> transposed qkT[b][n][m..m+3]
          u16x4 pk = {f2bf(acc[m2][n2][0] * qs), f2bf(acc[m2][n2][1] * qs),
                      f2bf(acc[m2][n2][2] * qs), f2bf(acc[m2][n2][3] * qs)};
          *(u16x4*)(qkT + ((size_t)b * NSP + n) * 512 + m) = pk;
        } else {           // v -> natural vbuf[b][m-512][n]
#pragma unroll
          for (int r = 0; r < 4; ++r)
            vbuf[((size_t)b * 256 + (m - 512 + r)) * NSP + n] =
                f2bf(acc[m2][n2][r]);
        }
      } else {
#pragma unroll
        for (int r = 0; r < 4; ++r)
          outf[((size_t)b * 256 + m + r) * NSP + n] =
              acc[m2][n2][r] + bias[m + r];
      }
    }
}

// ---------------------------------------------------------------------------
// MFMA flash attention (r11 structure, Kt stride 42->40 bank fix).
// 2-wave 128-thr blocks, 48 queries/wave (3 Q-frags) -> K/V fragment reads
// amortized 3x. KVBLK=128 (18 strips, 1 barrier each, double-buffered).
// Grid 768, XCD-swizzled (h = blockIdx%8) -> each (b,h)'s K/V L2-resident.
// P in-register (sigma trick); V stored PERMUTED so each V-fragment is one
// b128; Kt stride 40 (lanes 0-7 cover all 32 banks, 8-15 duplicate = 2-way
// free), Vs stride 138 (69 dw = 5 mod 32). Row-sum l via ones-MFMA.
// setprio(1) around MFMA clusters.
// ---------------------------------------------------------------------------
__global__ __launch_bounds__(128, 2) void attn_mfma(
    const u16* __restrict__ qkT, const u16* __restrict__ vbuf,
    u16* __restrict__ attnoT) {
  const int jb = blockIdx.x;
  const int h = jb & 7;
  const int qq = jb >> 3;
  const int it = qq % 24;
  const int b  = qq / 24;
  const int t = threadIdx.x, lane = t & 63, w = t >> 6;
  const int lo = lane & 15, g = lane >> 4;
  const int i0 = it * 96;

  const u16* qkTb = qkT + (size_t)b * NSP * 512;
  const u16* vb   = vbuf + ((size_t)b * 256 + h * 32) * NSP;
  u16* ob = attnoT + ((size_t)b * NSP + i0) * 256 + h * 32;

  __shared__ u16 Kt[2][128][40];   // [key j][d]
  __shared__ u16 Vs[2][32][138];   // [d][permuted j]

  // three Q fragments: queries i0 + w*48 + qh*16 + lo (pre-scaled by K1S)
  short8 qf[3];
#pragma unroll
  for (int qh = 0; qh < 3; ++qh)
    qf[qh] = *(const short8*)(qkTb +
              (size_t)(i0 + w * 48 + qh * 16 + lo) * 512 + h * 32 + g * 8);

  const int kr = t >> 2, kp = (t & 3) * 8;
  const int vr = t >> 4, vjp = (t & 15) * 8;
  const int pc0 = (vjp & ~31) | (8 * ((vjp >> 2) & 3) + 4 * ((vjp >> 4) & 1));
  const u16* ksrc = qkTb + 256 + h * 32 + kp;            // + (j0+row)*512
  const u16* vsrc = vb + (size_t)vr * NSP + vjp;         // + 8i*NSP + j0

  uint4 kv[4], vv[4];
#pragma unroll
  for (int i = 0; i < 4; ++i) {
    kv[i] = *(const uint4*)(ksrc + (size_t)(kr + 32 * i) * 512);
    vv[i] = *(const uint4*)(vsrc + (size_t)(8 * i) * NSP);
  }
#pragma unroll
  for (int i = 0; i < 4; ++i) {
    *(uint4*)&Kt[0][kr + 32 * i][kp] = kv[i];
    *(uint2*)&Vs[0][vr + 8 * i][pc0]     = make_uint2(vv[i].x, vv[i].y);
    *(uint2*)&Vs[0][vr + 8 * i][pc0 + 8] = make_uint2(vv[i].z, vv[i].w);
  }
  __syncthreads();

  short8 ones;
#pragma unroll
  for (int e = 0; e < 8; ++e) ones[e] = (short)0x3F80;  // bf16 1.0

  f32x4 a0[3], a1[3], al[3];
#pragma unroll
  for (int qh = 0; qh < 3; ++qh) {
    a0[qh] = (f32x4){0, 0, 0, 0};
    a1[qh] = (f32x4){0, 0, 0, 0};
    al[qh] = (f32x4){0, 0, 0, 0};
  }

  for (int s = 0; s < 18; ++s) {
    const int cur = s & 1;
    if (s + 1 < 18) {  // prefetch next strip into regs (hidden under compute)
      const int j0n = (s + 1) * 128;
#pragma unroll
      for (int i = 0; i < 4; ++i) {
        kv[i] = *(const uint4*)(ksrc + (size_t)(j0n + kr + 32 * i) * 512);
        vv[i] = *(const uint4*)(vsrc + j0n + (size_t)(8 * i) * NSP);
      }
    }

#pragma unroll
    for (int h2 = 0; h2 < 2; ++h2) {
      short8 kf0 = *(const short8*)&Kt[cur][h2 * 64 + lo][g * 8];
      short8 kf1 = *(const short8*)&Kt[cur][h2 * 64 + 16 + lo][g * 8];
      short8 kf2 = *(const short8*)&Kt[cur][h2 * 64 + 32 + lo][g * 8];
      short8 kf3 = *(const short8*)&Kt[cur][h2 * 64 + 48 + lo][g * 8];
      short8 vf00 = *(const short8*)&Vs[cur][lo][h2 * 64 + 8 * g];
      short8 vf01 = *(const short8*)&Vs[cur][lo][h2 * 64 + 32 + 8 * g];
      short8 vf10 = *(const short8*)&Vs[cur][16 + lo][h2 * 64 + 8 * g];
      short8 vf11 = *(const short8*)&Vs[cur][16 + lo][h2 * 64 + 32 + 8 * g];

#pragma unroll
      for (int qh = 0; qh < 3; ++qh) {
        __builtin_amdgcn_s_setprio(1);
        f32x4 sv0 = __builtin_amdgcn_mfma_f32_16x16x32_bf16(kf0, qf[qh], (f32x4){0,0,0,0}, 0, 0, 0);
        f32x4 sv1 = __builtin_amdgcn_mfma_f32_16x16x32_bf16(kf1, qf[qh], (f32x4){0,0,0,0}, 0, 0, 0);
        f32x4 sv2 = __builtin_amdgcn_mfma_f32_16x16x32_bf16(kf2, qf[qh], (f32x4){0,0,0,0}, 0, 0, 0);
        f32x4 sv3 = __builtin_amdgcn_mfma_f32_16x16x32_bf16(kf3, qf[qh], (f32x4){0,0,0,0}, 0, 0, 0);
        __builtin_amdgcn_s_setprio(0);

        f32x4 e0, e1, e2, e3;
#pragma unroll
        for (int r = 0; r < 4; ++r) {
          e0[r] = __builtin_amdgcn_exp2f(sv0[r]);
          e1[r] = __builtin_amdgcn_exp2f(sv1[r]);
          e2[r] = __builtin_amdgcn_exp2f(sv2[r]);
          e3[r] = __builtin_amdgcn_exp2f(sv3[r]);
        }
        uint4 P0 = {cvtpk(e0[0], e0[1]), cvtpk(e0[2], e0[3]),
                    cvtpk(e1[0], e1[1]), cvtpk(e1[2], e1[3])};
        uint4 P1 = {cvtpk(e2[0], e2[1]), cvtpk(e2[2], e2[3]),
                    cvtpk(e3[0], e3[1]), cvtpk(e3[2], e3[3])};
        short8 pf0 = __builtin_bit_cast(short8, P0);
        short8 pf1 = __builtin_bit_cast(short8, P1);

        __builtin_amdgcn_s_setprio(1);
        a0[qh] = __builtin_amdgcn_mfma_f32_16x16x32_bf16(pf0, vf00, a0[qh], 0, 0, 0);
        a1[qh] = __builtin_amdgcn_mfma_f32_16x16x32_bf16(pf0, vf10, a1[qh], 0, 0, 0);
        al[qh] = __builtin_amdgcn_mfma_f32_16x16x32_bf16(pf0, ones, al[qh], 0, 0, 0);
        a0[qh] = __builtin_amdgcn_mfma_f32_16x16x32_bf16(pf1, vf01, a0[qh], 0, 0, 0);
        a1[qh] = __builtin_amdgcn_mfma_f32_16x16x32_bf16(pf1, vf11, a1[qh], 0, 0, 0);
        al[qh] = __builtin_amdgcn_mfma_f32_16x16x32_bf16(pf1, ones, al[qh], 0, 0, 0);
        __builtin_amdgcn_s_setprio(0);
      }
    }

    if (s + 1 < 18) {  // write next strip into the other buffer
#pragma unroll
      for (int i = 0; i < 4; ++i) {
        *(uint4*)&Kt[cur ^ 1][kr + 32 * i][kp] = kv[i];
        *(uint2*)&Vs[cur ^ 1][vr + 8 * i][pc0]     = make_uint2(vv[i].x, vv[i].y);
        *(uint2*)&Vs[cur ^ 1][vr + 8 * i][pc0 + 8] = make_uint2(vv[i].z, vv[i].w);
      }
    }
    __syncthreads();
  }

  // ---- normalize + bf16 store to attnoT[n][c] ----
#pragma unroll
  for (int qh = 0; qh < 3; ++qh)
#pragma unroll
    for (int r = 0; r < 4; ++r) {
      float inv = 1.0f / al[qh][r];
      int row = w * 48 + qh * 16 + g * 4 + r;
      ob[(size_t)row * 256 + lo]      = f2bf(a0[qh][r] * inv);
      ob[(size_t)row * 256 + 16 + lo] = f2bf(a1[qh][r] * inv);
    }
}

// ---------------------------------------------------------------------------
extern "C" void kernel_launch(void* const* d_in, const int* in_sizes, int n_in,
                              void* d_out, int out_size, void* d_ws, size_t ws_size,
                              hipStream_t stream) {
  const float* x     = (const float*)d_in[0];  // [4][256][48][48]
  const float* w_qkv = (const float*)d_in[1];  // [768][256]
  const float* w_out = (const float*)d_in[2];  // [256][256]
  const float* b_out = (const float*)d_in[3];  // [256]
  float* out = (float*)d_out;                  // [4][256][2304]

  u16* xT     = (u16*)d_ws;                    // [4][2304][256]
  u16* qkT    = xT + (size_t)NB * NSP * 256;   // [4][2304][512]
  u16* vbuf   = qkT + (size_t)NB * NSP * 512;  // [4][256][2304]
  u16* attnoT = vbuf + (size_t)NB * 256 * NSP; // [4][2304][256]

  dim3 blk(256);
  transpose_x<<<dim3(NSP / 32, 8, NB), blk, 0, stream>>>(x, xT);
  // QKV projection (A = w_qkv fp32 fused-convert, B = xT) -> qkT + vbuf
  gemm_mfma<0><<<dim3(NSP / 64, 12, NB), blk, 0, stream>>>(
      w_qkv, xT, qkT, vbuf, nullptr, nullptr, NSP);
  // attention (r11 structure, Kt stride 40)
  attn_mfma<<<dim3(768), dim3(128), 0, stream>>>(qkT, vbuf, attnoT);
  // output projection + bias (A = w_out fp32 fused-convert, B = attnoT)
  gemm_mfma<1><<<dim3(NSP / 64, 4, NB), blk, 0, stream>>>(
      w_out, attnoT, nullptr, nullptr, out, b_out, NSP);
}

// Round 17
// 75.450 us; speedup vs baseline: 1.1446x; 1.1446x over previous
//
#include <hip/hip_runtime.h>
#include <hip/hip_bf16.h>

#define NSP 2304   // 48*48 spatial
#define NB  4      // batch

typedef unsigned short u16;
typedef __attribute__((ext_vector_type(8))) short short8;
typedef __attribute__((ext_vector_type(4))) float f32x4;
typedef __attribute__((ext_vector_type(4))) unsigned short u16x4;

// scale * log2(e), folded into Q at QKV-GEMM epilogue: softmax p = exp2(S)
#define K1S 0.25508040852656425f

static __device__ inline u16 f2bf(float f) {
  return __builtin_bit_cast(unsigned short, __float2bfloat16(f));
}
// packed f32x2 -> bf16x2 (RNE), single VALU inst
static __device__ inline unsigned cvtpk(float a, float b) {
  unsigned r;
  asm("v_cvt_pk_bf16_f32 %0, %1, %2" : "=v"(r) : "v"(a), "v"(b));
  return r;
}

// ---------------------------------------------------------------------------
// prep 1: w_qkv (768*256) and w_out (256*256) fp32 -> bf16, one region.
// ---------------------------------------------------------------------------
__global__ __launch_bounds__(256) void convert_w(
    const float* __restrict__ wq, const float* __restrict__ wo,
    u16* __restrict__ dst) {
  int i = (blockIdx.x * 256 + threadIdx.x) * 4;
  float4 v;
  if (i < 196608) v = *(const float4*)(wq + i);
  else            v = *(const float4*)(wo + (i - 196608));
  u16x4 p = {f2bf(v.x), f2bf(v.y), f2bf(v.z), f2bf(v.w)};
  *(u16x4*)(dst + i) = p;
}

// ---------------------------------------------------------------------------
// prep 2: x fp32 [b][256][2304] -> xT bf16 [b][2304][256]
// ---------------------------------------------------------------------------
__global__ __launch_bounds__(256) void transpose_x(
    const float* __restrict__ x, u16* __restrict__ xT) {
  __shared__ float tile[32][33];
  const int t = threadIdx.x;
  const int n0 = blockIdx.x * 32, c0 = blockIdx.y * 32, b = blockIdx.z;
  const float* xb = x + ((size_t)b * 256 + c0) * NSP + n0;
#pragma unroll
  for (int e = t; e < 1024; e += 256) {
    int cc = e >> 5, nn = e & 31;
    tile[cc][nn] = xb[(size_t)cc * NSP + nn];
  }
  __syncthreads();
  u16* xTb = xT + ((size_t)b * NSP + n0) * 256 + c0;
#pragma unroll
  for (int e = t; e < 1024; e += 256) {
    int nn = e >> 5, cc = e & 31;
    xTb[(size_t)nn * 256 + cc] = f2bf(tile[cc][nn]);
  }
}

// ---------------------------------------------------------------------------
// bf16 MFMA GEMM (r11 structure, bf16 A): D = A (Mx256) * B[b](Nx256)^T
// 64x64 tile, 4 waves (2x2 of 32x32), whole K=256 staged once.
// EPI 0: rows <256 q (pre-scaled K1S), 256..511 k -> qkT[b][n][512] bf16;
//        rows >=512 v -> vbuf[b][256][2304] bf16.
// EPI 1: fp32 out + bias.
// ---------------------------------------------------------------------------
template <int EPI>
__global__ __launch_bounds__(256) void gemm_mfma(
    const u16* __restrict__ A, const u16* __restrict__ B,
    u16* __restrict__ qkT, u16* __restrict__ vbuf,
    float* __restrict__ outf, const float* __restrict__ bias, int N) {
  __shared__ u16 As[64][264];
  __shared__ u16 Bs[64][264];
  const int t = threadIdx.x, lane = t & 63, wid = t >> 6;
  const int lo = lane & 15, g = lane >> 4;
  const int wr = wid >> 1, wc = wid & 1;
  const int row0 = blockIdx.y * 64, col0 = blockIdx.x * 64, b = blockIdx.z;

  const int sr = t >> 2, c4 = t & 3;
  const u16* Arow = A + (size_t)(row0 + sr) * 256;
  const u16* Brow = B + ((size_t)b * N + col0 + sr) * 256;
#pragma unroll
  for (int i = 0; i < 8; ++i) {
    int col = (c4 + 4 * i) * 8;
    *(uint4*)&As[sr][col] = *(const uint4*)&Arow[col];
    *(uint4*)&Bs[sr][col] = *(const uint4*)&Brow[col];
  }
  __syncthreads();

  f32x4 acc[2][2];
#pragma unroll
  for (int i = 0; i < 2; ++i)
#pragma unroll
    for (int j = 0; j < 2; ++j) acc[i][j] = (f32x4){0, 0, 0, 0};

  const int ar0 = wr * 32 + lo, br0 = wc * 32 + lo;
#pragma unroll
  for (int kk = 0; kk < 8; ++kk) {
    int kc = kk * 32 + g * 8;
    short8 a0 = *(const short8*)&As[ar0][kc];
    short8 a1 = *(const short8*)&As[ar0 + 16][kc];
    short8 b0 = *(const short8*)&Bs[br0][kc];
    short8 b1 = *(const short8*)&Bs[br0 + 16][kc];
    acc[0][0] = __builtin_amdgcn_mfma_f32_16x16x32_bf16(a0, b0, acc[0][0], 0, 0, 0);
    acc[0][1] = __builtin_amdgcn_mfma_f32_16x16x32_bf16(a0, b1, acc[0][1], 0, 0, 0);
    acc[1][0] = __builtin_amdgcn_mfma_f32_16x16x32_bf16(a1, b0, acc[1][0], 0, 0, 0);
    acc[1][1] = __builtin_amdgcn_mfma_f32_16x16x32_bf16(a1, b1, acc[1][1], 0, 0, 0);
  }

  const float qs = (EPI == 0 && row0 < 256) ? K1S : 1.0f;
#pragma unroll
  for (int m2 = 0; m2 < 2; ++m2)
#pragma unroll
    for (int n2 = 0; n2 < 2; ++n2) {
      int m = row0 + wr * 32 + m2 * 16 + g * 4;
      int n = col0 + wc * 32 + n2 * 16 + lo;
      if constexpr (EPI == 0) {
        if (row0 < 512) {  // q,k -> transposed qkT[b][n][m..m+3]
          u16x4 pk = {f2bf(acc[m2][n2][0] * qs), f2bf(acc[m2][n2][1] * qs),
                      f2bf(acc[m2][n2][2] * qs), f2bf(acc[m2][n2][3] * qs)};
          *(u16x4*)(qkT + ((size_t)b * NSP + n) * 512 + m) = pk;
        } else {           // v -> natural vbuf[b][m-512][n]
#pragma unroll
          for (int r = 0; r < 4; ++r)
            vbuf[((size_t)b * 256 + (m - 512 + r)) * NSP + n] =
                f2bf(acc[m2][n2][r]);
        }
      } else {
#pragma unroll
        for (int r = 0; r < 4; ++r)
          outf[((size_t)b * 256 + m + r) * NSP + n] =
              acc[m2][n2][r] + bias[m + r];
      }
    }
}

// ---------------------------------------------------------------------------
// MFMA flash attention, BLOCK-LEVEL KEY-SPLIT (2x TLP at 48 q/wave).
// Grid 1536: jb -> h=jb&7 (XCD), kp=key-half, it (24 tiles of 96 q), b.
// Each block = exact r16 body on 1152 keys: 18 strips of 64 keys,
// double-buffered Kt[64][40] / Vs[32][70] (perm V, one b128/frag),
// P in-register (sigma), ones-MFMA rowsum, setprio MFMA clusters.
// LDS 19.2 KB -> 8 blocks/CU cap; 6 resident -> 12 waves/CU = 3/SIMD.
// No-max exp2 softmax => partials plain-add: write (a0,a1,l) fp32 to
// part[kp][grp][33][96]; merge kernel combines.
// ---------------------------------------------------------------------------
__global__ __launch_bounds__(128, 2) void attn_mfma(
    const u16* __restrict__ qkT, const u16* __restrict__ vbuf,
    float* __restrict__ part) {
  const int jb = blockIdx.x;
  const int h  = jb & 7;
  const int q2 = jb >> 3;        // [0,192)
  const int kp = q2 & 1;
  const int q3 = q2 >> 1;        // [0,96)
  const int it = q3 % 24;
  const int b  = q3 / 24;
  const int grp = q3 * 8 + h;    // (b*24+it)*8 + h
  const int t = threadIdx.x, lane = t & 63, w = t >> 6;
  const int lo = lane & 15, g = lane >> 4;
  const int i0 = it * 96;
  const int j0base = kp * 1152;

  const u16* qkTb = qkT + (size_t)b * NSP * 512;
  const u16* vb   = vbuf + ((size_t)b * 256 + h * 32) * NSP;

  __shared__ u16 Kt[2][64][40];   // [key j][d]
  __shared__ u16 Vs[2][32][70];   // [d][permuted j]

  // three Q fragments: queries i0 + w*48 + qh*16 + lo (pre-scaled by K1S)
  short8 qf[3];
#pragma unroll
  for (int qh = 0; qh < 3; ++qh)
    qf[qh] = *(const short8*)(qkTb +
              (size_t)(i0 + w * 48 + qh * 16 + lo) * 512 + h * 32 + g * 8);

  // staging (128 thr, 64-key strips): 2 K-chunks + 2 V-chunks per thread
  const int kr = t >> 2, kpd = (t & 3) * 8;   // K rows kr, kr+32
  const int vr = t >> 3, vjp = (t & 7) * 8;   // V rows vr, vr+16
  const int pc0 = (vjp & ~31) | (8 * ((vjp >> 2) & 3) + 4 * ((vjp >> 4) & 1));
  const u16* ksrc = qkTb + 256 + h * 32 + kpd;           // + j*512
  const u16* vsrc = vb + (size_t)vr * NSP + vjp;         // + j0, +16*NSP

  uint4 kv[2], vv[2];
  kv[0] = *(const uint4*)(ksrc + (size_t)(j0base + kr) * 512);
  kv[1] = *(const uint4*)(ksrc + (size_t)(j0base + kr + 32) * 512);
  vv[0] = *(const uint4*)(vsrc + j0base);
  vv[1] = *(const uint4*)(vsrc + j0base + (size_t)16 * NSP);
  *(uint4*)&Kt[0][kr][kpd]      = kv[0];
  *(uint4*)&Kt[0][kr + 32][kpd] = kv[1];
  *(uint2*)&Vs[0][vr][pc0]           = make_uint2(vv[0].x, vv[0].y);
  *(uint2*)&Vs[0][vr][pc0 + 8]       = make_uint2(vv[0].z, vv[0].w);
  *(uint2*)&Vs[0][vr + 16][pc0]      = make_uint2(vv[1].x, vv[1].y);
  *(uint2*)&Vs[0][vr + 16][pc0 + 8]  = make_uint2(vv[1].z, vv[1].w);
  __syncthreads();

  short8 ones;
#pragma unroll
  for (int e = 0; e < 8; ++e) ones[e] = (short)0x3F80;  // bf16 1.0

  f32x4 a0[3], a1[3], al[3];
#pragma unroll
  for (int qh = 0; qh < 3; ++qh) {
    a0[qh] = (f32x4){0, 0, 0, 0};
    a1[qh] = (f32x4){0, 0, 0, 0};
    al[qh] = (f32x4){0, 0, 0, 0};
  }

  for (int s = 0; s < 18; ++s) {
    const int cur = s & 1;
    if (s + 1 < 18) {  // prefetch next strip into regs
      const int j0n = j0base + (s + 1) * 64;
      kv[0] = *(const uint4*)(ksrc + (size_t)(j0n + kr) * 512);
      kv[1] = *(const uint4*)(ksrc + (size_t)(j0n + kr + 32) * 512);
      vv[0] = *(const uint4*)(vsrc + j0n);
      vv[1] = *(const uint4*)(vsrc + j0n + (size_t)16 * NSP);
    }

    short8 kf0 = *(const short8*)&Kt[cur][lo][g * 8];
    short8 kf1 = *(const short8*)&Kt[cur][16 + lo][g * 8];
    short8 kf2 = *(const short8*)&Kt[cur][32 + lo][g * 8];
    short8 kf3 = *(const short8*)&Kt[cur][48 + lo][g * 8];
    short8 vf00 = *(const short8*)&Vs[cur][lo][8 * g];
    short8 vf01 = *(const short8*)&Vs[cur][lo][32 + 8 * g];
    short8 vf10 = *(const short8*)&Vs[cur][16 + lo][8 * g];
    short8 vf11 = *(const short8*)&Vs[cur][16 + lo][32 + 8 * g];

#pragma unroll
    for (int qh = 0; qh < 3; ++qh) {
      __builtin_amdgcn_s_setprio(1);
      f32x4 sv0 = __builtin_amdgcn_mfma_f32_16x16x32_bf16(kf0, qf[qh], (f32x4){0,0,0,0}, 0, 0, 0);
      f32x4 sv1 = __builtin_amdgcn_mfma_f32_16x16x32_bf16(kf1, qf[qh], (f32x4){0,0,0,0}, 0, 0, 0);
      f32x4 sv2 = __builtin_amdgcn_mfma_f32_16x16x32_bf16(kf2, qf[qh], (f32x4){0,0,0,0}, 0, 0, 0);
      f32x4 sv3 = __builtin_amdgcn_mfma_f32_16x16x32_bf16(kf3, qf[qh], (f32x4){0,0,0,0}, 0, 0, 0);
      __builtin_amdgcn_s_setprio(0);

      f32x4 e0, e1, e2, e3;
#pragma unroll
      for (int r = 0; r < 4; ++r) {
        e0[r] = __builtin_amdgcn_exp2f(sv0[r]);
        e1[r] = __builtin_amdgcn_exp2f(sv1[r]);
        e2[r] = __builtin_amdgcn_exp2f(sv2[r]);
        e3[r] = __builtin_amdgcn_exp2f(sv3[r]);
      }
      uint4 P0 = {cvtpk(e0[0], e0[1]), cvtpk(e0[2], e0[3]),
                  cvtpk(e1[0], e1[1]), cvtpk(e1[2], e1[3])};
      uint4 P1 = {cvtpk(e2[0], e2[1]), cvtpk(e2[2], e2[3]),
                  cvtpk(e3[0], e3[1]), cvtpk(e3[2], e3[3])};
      short8 pf0 = __builtin_bit_cast(short8, P0);
      short8 pf1 = __builtin_bit_cast(short8, P1);

      __builtin_amdgcn_s_setprio(1);
      a0[qh] = __builtin_amdgcn_mfma_f32_16x16x32_bf16(pf0, vf00, a0[qh], 0, 0, 0);
      a1[qh] = __builtin_amdgcn_mfma_f32_16x16x32_bf16(pf0, vf10, a1[qh], 0, 0, 0);
      al[qh] = __builtin_amdgcn_mfma_f32_16x16x32_bf16(pf0, ones, al[qh], 0, 0, 0);
      a0[qh] = __builtin_amdgcn_mfma_f32_16x16x32_bf16(pf1, vf01, a0[qh], 0, 0, 0);
      a1[qh] = __builtin_amdgcn_mfma_f32_16x16x32_bf16(pf1, vf11, a1[qh], 0, 0, 0);
      al[qh] = __builtin_amdgcn_mfma_f32_16x16x32_bf16(pf1, ones, al[qh], 0, 0, 0);
      __builtin_amdgcn_s_setprio(0);
    }

    if (s + 1 < 18) {  // write next strip into the other buffer
      *(uint4*)&Kt[cur ^ 1][kr][kpd]      = kv[0];
      *(uint4*)&Kt[cur ^ 1][kr + 32][kpd] = kv[1];
      *(uint2*)&Vs[cur ^ 1][vr][pc0]          = make_uint2(vv[0].x, vv[0].y);
      *(uint2*)&Vs[cur ^ 1][vr][pc0 + 8]      = make_uint2(vv[0].z, vv[0].w);
      *(uint2*)&Vs[cur ^ 1][vr + 16][pc0]     = make_uint2(vv[1].x, vv[1].y);
      *(uint2*)&Vs[cur ^ 1][vr + 16][pc0 + 8] = make_uint2(vv[1].z, vv[1].w);
    }
    __syncthreads();
  }

  // ---- write fp32 partials: part[kp][grp][col 0..32][row 0..95] ----
  float* pg = part + ((size_t)kp * 768 + grp) * (33 * 96);
#pragma unroll
  for (int qh = 0; qh < 3; ++qh) {
    int row = w * 48 + qh * 16 + g * 4;
    *(f32x4*)&pg[(size_t)lo * 96 + row]        = a0[qh];
    *(f32x4*)&pg[(size_t)(16 + lo) * 96 + row] = a1[qh];
    if (lo == 0) *(f32x4*)&pg[(size_t)32 * 96 + row] = al[qh];
  }
}

// ---------------------------------------------------------------------------
// merge: out[row][c] = (p0[c][row]+p1[c][row]) / (l0+l1) -> attnoT bf16.
// Grid 768 (one per grp), 128 thr (96 active, one per query row).
// ---------------------------------------------------------------------------
__global__ __launch_bounds__(128) void merge_attn(
    const float* __restrict__ part, u16* __restrict__ attnoT) {
  const int grp = blockIdx.x;
  const int h = grp & 7, q3 = grp >> 3;
  const int it = q3 % 24, b = q3 / 24;
  const int t = threadIdx.x;
  if (t >= 96) return;
  const float* p0 = part + (size_t)grp * (33 * 96);
  const float* p1 = part + ((size_t)768 + grp) * (33 * 96);
  float inv = 1.0f / (p0[32 * 96 + t] + p1[32 * 96 + t]);
  u16* ob = attnoT + ((size_t)b * NSP + it * 96 + t) * 256 + h * 32;
#pragma unroll
  for (int c4 = 0; c4 < 8; ++c4) {
    u16x4 o;
#pragma unroll
    for (int j = 0; j < 4; ++j) {
      int c = c4 * 4 + j;
      o[j] = f2bf((p0[c * 96 + t] + p1[c * 96 + t]) * inv);
    }
    *(u16x4*)&ob[c4 * 4] = o;
  }
}

// ---------------------------------------------------------------------------
extern "C" void kernel_launch(void* const* d_in, const int* in_sizes, int n_in,
                              void* d_out, int out_size, void* d_ws, size_t ws_size,
                              hipStream_t stream) {
  const float* x     = (const float*)d_in[0];  // [4][256][48][48]
  const float* w_qkv = (const float*)d_in[1];  // [768][256]
  const float* w_out = (const float*)d_in[2];  // [256][256]
  const float* b_out = (const float*)d_in[3];  // [256]
  float* out = (float*)d_out;                  // [4][256][2304]

  u16* wbf    = (u16*)d_ws;                    // wqkv 196608 then wout 65536
  u16* xT     = wbf + 262144;                  // [4][2304][256]
  u16* qkT    = xT + (size_t)NB * NSP * 256;   // [4][2304][512]
  u16* vbuf   = qkT + (size_t)NB * NSP * 512;  // [4][256][2304]
  u16* attnoT = vbuf + (size_t)NB * 256 * NSP; // [4][2304][256]
  float* part = (float*)(attnoT + (size_t)NB * NSP * 256);  // [2][768][33][96]

  dim3 blk(256);
  convert_w<<<256, blk, 0, stream>>>(w_qkv, w_out, wbf);
  transpose_x<<<dim3(NSP / 32, 8, NB), blk, 0, stream>>>(x, xT);
  gemm_mfma<0><<<dim3(NSP / 64, 12, NB), blk, 0, stream>>>(
      wbf, xT, qkT, vbuf, nullptr, nullptr, NSP);
  attn_mfma<<<dim3(1536), dim3(128), 0, stream>>>(qkT, vbuf, part);
  merge_attn<<<dim3(768), dim3(128), 0, stream>>>(part, attnoT);
  gemm_mfma<1><<<dim3(NSP / 64, 4, NB), blk, 0, stream>>>(
      wbf + 196608, attnoT, nullptr, nullptr, out, b_out, NSP);
}